// Round 20
// baseline (216.892 us; speedup 1.0000x reference)
//
#include <hip/hip_runtime.h>
#include <math.h>

#define PI_F 3.14159265358979323846f
#define ST 66   // float2 row stride of the 64x64 complex grid

typedef __attribute__((ext_vector_type(8))) short short8;
typedef __attribute__((ext_vector_type(4))) float f32x4;
typedef __attribute__((ext_vector_type(4))) unsigned short u16x4;
typedef __attribute__((ext_vector_type(8))) unsigned short u16x8;
typedef __attribute__((ext_vector_type(4))) unsigned uint4v;

static __device__ __forceinline__ int sw(int row, int intra) {
    return row * ST + (intra ^ (row & 7));
}

static __device__ __forceinline__ unsigned short f2bf(float x) {
    unsigned u = __float_as_uint(x);
    unsigned r = (u + 0x7FFF + ((u >> 16) & 1)) >> 16;
    return (unsigned short)r;
}
static __device__ __forceinline__ float bf2f(unsigned short u) {
    return __uint_as_float(((unsigned)u) << 16);
}
static __device__ __forceinline__ float2 unpk(unsigned v) {
    return make_float2(bf2f((unsigned short)(v & 0xffff)), bf2f((unsigned short)(v >> 16)));
}

static __device__ __forceinline__ float2 cadd(float2 a, float2 b) { return make_float2(a.x + b.x, a.y + b.y); }
static __device__ __forceinline__ float2 csub(float2 a, float2 b) { return make_float2(a.x - b.x, a.y - b.y); }
static __device__ __forceinline__ float2 cmul(float2 a, float2 b) { return make_float2(a.x * b.x - a.y * b.y, a.x * b.y + a.y * b.x); }
static __device__ __forceinline__ float2 cmulc(float2 a, float2 b) { return make_float2(a.x * b.x + a.y * b.y, a.y * b.x - a.x * b.y); }

template <int S>
static __device__ __forceinline__ void dft8(float2* z) {
    const float RT = 0.70710678118654752440f;
    float2 ee0 = cadd(z[0], z[4]), ee1 = csub(z[0], z[4]);
    float2 eo0 = cadd(z[2], z[6]), eo1 = csub(z[2], z[6]);
    float2 oe0 = cadd(z[1], z[5]), oe1 = csub(z[1], z[5]);
    float2 oo0 = cadd(z[3], z[7]), oo1 = csub(z[3], z[7]);
    float2 ieo1 = make_float2(-S * eo1.y, S * eo1.x);
    float2 ioo1 = make_float2(-S * oo1.y, S * oo1.x);
    float2 E0 = cadd(ee0, eo0), E2 = csub(ee0, eo0);
    float2 E1 = cadd(ee1, ieo1), E3 = csub(ee1, ieo1);
    float2 O0 = cadd(oe0, oo0), O2 = csub(oe0, oo0);
    float2 O1 = cadd(oe1, ioo1), O3 = csub(oe1, ioo1);
    float2 w1O1 = make_float2(RT * (O1.x - S * O1.y), RT * (S * O1.x + O1.y));
    float2 w3O3 = make_float2(RT * (-O3.x - S * O3.y), RT * (S * O3.x - O3.y));
    float2 iO2  = make_float2(-S * O2.y, S * O2.x);
    z[0] = cadd(E0, O0);   z[4] = csub(E0, O0);
    z[1] = cadd(E1, w1O1); z[5] = csub(E1, w1O1);
    z[2] = cadd(E2, iO2);  z[6] = csub(E2, iO2);
    z[3] = cadd(E3, w3O3); z[7] = csub(E3, w3O3);
}

// ---- 512-thread FFT phases: 1 slot per thread (s = tid in [0,512)) ----
template <int S>
static __device__ __forceinline__ void fftRowsA(float2* G, const float2* twl, int s) {
    int row = s >> 3, b = s & 7;
    float2 z[8];
#pragma unroll
    for (int a = 0; a < 8; ++a) z[a] = G[sw(row, 8 * a + b)];
    dft8<S>(z);
#pragma unroll
    for (int c = 0; c < 8; ++c) {
        float2 t = twl[(b * c) & 63];
        G[sw(row, 8 * c + b)] = (S < 0) ? cmul(z[c], t) : cmulc(z[c], t);
    }
}
template <int S>
static __device__ __forceinline__ void fftRowsB(float2* G, int s) {
    int r0 = s >> 3, c = s & 7;
    float2 z0[8];
#pragma unroll
    for (int b = 0; b < 8; ++b) z0[b] = G[sw(r0, 8 * c + b)];
    dft8<S>(z0);
    __syncthreads();
#pragma unroll
    for (int d = 0; d < 8; ++d) G[sw(r0, c + 8 * d)] = z0[d];
}
template <int S>
static __device__ __forceinline__ void fftColsA(float2* G, const float2* twl, int s) {
    int col = s & 63, b = s >> 6;
    float2 z[8];
#pragma unroll
    for (int a = 0; a < 8; ++a) z[a] = G[sw(8 * a + b, col)];
    dft8<S>(z);
#pragma unroll
    for (int c = 0; c < 8; ++c) {
        float2 t = twl[(b * c) & 63];
        G[sw(8 * c + b, col)] = (S < 0) ? cmul(z[c], t) : cmulc(z[c], t);
    }
}
template <int S>
static __device__ __forceinline__ void fftColsB(float2* G, int s) {
    int col = s & 63, c0 = s >> 6;
    float2 z0[8];
#pragma unroll
    for (int b = 0; b < 8; ++b) z0[b] = G[sw(8 * c0 + b, col)];
    dft8<S>(z0);
    __syncthreads();
#pragma unroll
    for (int d = 0; d < 8; ++d) G[sw(c0 + 8 * d, col)] = z0[d];
}

// ---------------------------------------------------------------- k_params
__global__ __launch_bounds__(256) void k_params(const float* __restrict__ stats,
                                                const float* __restrict__ gw,
                                                const float* __restrict__ gb,
                                                const float* __restrict__ dts,
                                                float2* __restrict__ A,
                                                float2* __restrict__ Xt) {
    int idx = blockIdx.x * 256 + threadIdx.x;
    int c = idx & 127;
    int bt = idx >> 7;
    const float* st = stats + bt * 128;
    float nu = gb[c], om = gb[c + 128];
    for (int k = 0; k < 128; ++k) {
        float s = st[k];
        nu += s * gw[k * 256 + c];
        om += s * gw[k * 256 + c + 128];
    }
    float dt = dts[bt];
    float lre = -fabsf(nu);
    float lim = om;
    float mag = sqrtf(lre * lre + lim * lim);
    float er = expf(lre * dt);
    float sn, cs;
    sincosf(lim * dt, &sn, &cs);
    float2 Av = make_float2(er * cs, er * sn);
    float2 X;
    if (mag < 1e-6f) {
        X = make_float2(dt, 0.f);
    } else {
        float ar = Av.x - 1.f, ai = Av.y;
        float inv = 1.f / (mag * mag);
        X = make_float2((ar * lre + ai * lim) * inv, (ai * lre - ar * lim) * inv);
    }
    A[idx] = Av;
    Xt[idx] = X;
}

// ---------------------------------------------------------------- k_rfft2s (512 threads)
__global__ __launch_bounds__(512) void k_rfft2s(const float* __restrict__ xin,
                                                unsigned* __restrict__ Sb,
                                                float* __restrict__ stats) {
    int p = blockIdx.x, tid = threadIdx.x;
    __shared__ float2 G[64 * ST], twl[64];
    __shared__ float red[16];
    if (tid < 64) {
        float sn, cs;
        sincosf(-(2.0f * PI_F / 64.0f) * (float)tid, &sn, &cs);
        twl[tid] = make_float2(cs, sn);
    }
    const float* x0 = xin + (size_t)(2 * p) * 4096;
    const float* x1 = x0 + 4096;
    float s0 = 0.f, s1 = 0.f;
    for (int i4 = tid; i4 < 1024; i4 += 512) {
        float4 a = ((const float4*)x0)[i4];
        float4 b = ((const float4*)x1)[i4];
        s0 += a.x + a.y + a.z + a.w;
        s1 += b.x + b.y + b.z + b.w;
        int r = i4 >> 4, w = (i4 & 15) << 2;
        G[sw(r, w + 0)] = make_float2(a.x, b.x);
        G[sw(r, w + 1)] = make_float2(a.y, b.y);
        G[sw(r, w + 2)] = make_float2(a.z, b.z);
        G[sw(r, w + 3)] = make_float2(a.w, b.w);
    }
    for (int off = 32; off > 0; off >>= 1) {
        s0 += __shfl_xor(s0, off, 64);
        s1 += __shfl_xor(s1, off, 64);
    }
    if ((tid & 63) == 0) { red[(tid >> 6) * 2] = s0; red[(tid >> 6) * 2 + 1] = s1; }
    __syncthreads();
    if (tid < 2) {
        float t = 0.f;
#pragma unroll
        for (int w6 = 0; w6 < 8; ++w6) t += red[tid + 2 * w6];
        stats[2 * p + tid] = t * (1.0f / 4096.0f);
    }
    fftRowsA<-1>(G, twl, tid); __syncthreads();
    fftRowsB<-1>(G, tid);      __syncthreads();
    fftColsA<-1>(G, twl, tid); __syncthreads();
    fftColsB<-1>(G, tid);      __syncthreads();

    unsigned* o0 = Sb + (size_t)(2 * p) * 2112;
    unsigned* o1 = o0 + 2112;
    for (int i = tid; i < 2112; i += 512) {
        int my = i / 33, mx = i - my * 33;
        float2 Zk = G[sw(my, mx)];
        float2 Zm = G[sw((64 - my) & 63, (64 - mx) & 63)];
        float a0 = (Zk.x + Zm.x) * (0.5f / 64.0f);
        float a1 = (Zk.y - Zm.y) * (0.5f / 64.0f);
        float b0 = (Zk.y + Zm.y) * (0.5f / 64.0f);
        float b1 = (Zm.x - Zk.x) * (0.5f / 64.0f);
        o0[i] = (unsigned)f2bf(a0) | ((unsigned)f2bf(a1) << 16);
        o1[i] = (unsigned)f2bf(b0) | ((unsigned)f2bf(b1) << 16);
    }
}

// ---------------------------------------------------------------- k_scan (x4 vectorized, 16B/lane)
__global__ __launch_bounds__(256) void k_scan(unsigned* __restrict__ Sb,
                                              const float2* __restrict__ A,
                                              const float2* __restrict__ Xt) {
    int tid = blockIdx.x * 256 + threadIdx.x;   // 135168 total = 528 blocks
    int s = tid % 528;
    int c = (tid / 528) & 127;
    int b = tid / (528 * 128);
    float2 h0 = make_float2(0.f, 0.f), h1 = h0, h2 = h0, h3 = h0;
    for (int t = 0; t < 16; ++t) {
        int bt = b * 16 + t;
        float2 a = A[bt * 128 + c];
        float2 xt = Xt[bt * 128 + c];
        size_t off = ((size_t)(bt * 128 + c)) * 2112 + 4 * s;
        uint4v v = *(uint4v*)(Sb + off);
        float2 x0 = cmul(unpk(v[0]), xt);
        float2 x1 = cmul(unpk(v[1]), xt);
        float2 x2 = cmul(unpk(v[2]), xt);
        float2 x3 = cmul(unpk(v[3]), xt);
        h0 = make_float2(a.x * h0.x - a.y * h0.y + x0.x, a.x * h0.y + a.y * h0.x + x0.y);
        h1 = make_float2(a.x * h1.x - a.y * h1.y + x1.x, a.x * h1.y + a.y * h1.x + x1.y);
        h2 = make_float2(a.x * h2.x - a.y * h2.y + x2.x, a.x * h2.y + a.y * h2.x + x2.y);
        h3 = make_float2(a.x * h3.x - a.y * h3.y + x3.x, a.x * h3.y + a.y * h3.x + x3.y);
        uint4v o;
        o[0] = (unsigned)f2bf(h0.x) | ((unsigned)f2bf(h0.y) << 16);
        o[1] = (unsigned)f2bf(h1.x) | ((unsigned)f2bf(h1.y) << 16);
        o[2] = (unsigned)f2bf(h2.x) | ((unsigned)f2bf(h2.y) << 16);
        o[3] = (unsigned)f2bf(h3.x) | ((unsigned)f2bf(h3.y) << 16);
        *(uint4v*)(Sb + off) = o;
    }
}

// ---------------------------------------------------------------- k_irfft2b (512 threads)
__global__ __launch_bounds__(512) void k_irfft2b(const unsigned* __restrict__ Sb,
                                                 unsigned short* __restrict__ hb) {
    int p = blockIdx.x, tid = threadIdx.x;
    __shared__ float2 G[64 * ST], twl[64];
    if (tid < 64) {
        float sn, cs;
        sincosf(-(2.0f * PI_F / 64.0f) * (float)tid, &sn, &cs);
        twl[tid] = make_float2(cs, sn);
    }
    const unsigned* i0 = Sb + (size_t)(2 * p) * 2112;
    const unsigned* i1 = i0 + 2112;
    for (int i = tid; i < 1984; i += 512) {
        int mx = 1 + i % 31, my = i / 31;
        int idx = my * 33 + mx;
        float2 a = unpk(i0[idx]);
        float2 b = unpk(i1[idx]);
        G[sw(my, mx)] = make_float2(a.x - b.y, a.y + b.x);
        G[sw((64 - my) & 63, 64 - mx)] = make_float2(a.x + b.y, b.x - a.y);
    }
    if (tid < 64) {
        int mx = (tid >= 32) ? 32 : 0;
        int r = tid & 31;
        if (r == 0) {
#pragma unroll
            for (int q = 0; q < 2; ++q) {
                int my = q * 32;
                float2 a = unpk(i0[my * 33 + mx]);
                float2 b = unpk(i1[my * 33 + mx]);
                G[sw(my, mx)] = make_float2(a.x, b.x);     // imag dropped
            }
        } else {
            int my = r, my2 = 64 - r;
            float2 A0 = unpk(i0[my * 33 + mx]),  B0 = unpk(i0[my2 * 33 + mx]);
            float2 A1 = unpk(i1[my * 33 + mx]),  B1 = unpk(i1[my2 * 33 + mx]);
            float2 V0 = make_float2((A0.x + B0.x) * 0.5f, (A0.y - B0.y) * 0.5f);
            float2 V1 = make_float2((A1.x + B1.x) * 0.5f, (A1.y - B1.y) * 0.5f);
            G[sw(my, mx)]  = make_float2(V0.x - V1.y, V0.y + V1.x);
            G[sw(my2, mx)] = make_float2(V0.x + V1.y, V1.x - V0.y);
        }
    }
    __syncthreads();
    fftColsA<1>(G, twl, tid); __syncthreads();
    fftColsB<1>(G, tid);      __syncthreads();
    fftRowsA<1>(G, twl, tid); __syncthreads();
    fftRowsB<1>(G, tid);      __syncthreads();

    unsigned short* h0 = hb + (size_t)(2 * p) * 4096;
    unsigned short* h1 = h0 + 4096;
    for (int i4 = tid; i4 < 1024; i4 += 512) {
        int r = i4 >> 4, w = (i4 & 15) << 2;
        u16x4 oa, ob;
#pragma unroll
        for (int e = 0; e < 4; ++e) {
            float2 v = G[sw(r, w + e)];
            oa[e] = f2bf(v.x * (1.0f / 64.0f));
            ob[e] = f2bf(v.y * (1.0f / 64.0f));
        }
        ((u16x4*)h0)[i4] = oa;
        ((u16x4*)h1)[i4] = ob;
    }
}

// ---------------------------------------------------------------- k_wprep
__global__ __launch_bounds__(256) void k_wprep(const float* __restrict__ cwa,
                                               const float* __restrict__ cwb,
                                               unsigned short* __restrict__ Wb) {
    int idx = blockIdx.x * 256 + threadIdx.x;
    int kl = idx & 31;
    int m = (idx >> 5) & 127;
    int tcb = idx >> 12;
    int cb = tcb & 3, t = tcb >> 2;
    int ci = cb * 32 + kl;
    int mm = m & 63, cc = ci & 63;
    float w;
    if (m < 64) w = (ci < 64) ? cwa[(mm * 64 + cc) * 9 + t] : -cwb[(mm * 64 + cc) * 9 + t];
    else        w = (ci < 64) ? cwb[(mm * 64 + cc) * 9 + t] :  cwa[(mm * 64 + cc) * 9 + t];
    if (m == ci && t == 4) w += 1.0f;
    Wb[idx] = f2bf(w);
}

// ---------------------------------------------------------------- k_conv_mfma (512 threads, 8 waves)
// Same 2-row tile / 64KB LDS / grid as the best 256-thread version (identical
// FETCH & L2 locality) but 8 waves split output cols: 2 rows x 2 ch-halves x
// 2 col-halves. 4 waves/SIMD (vs 2) doubles latency hiding; acc halves to
// 32 VGPR so 128-VGPR budget holds.
__global__ __launch_bounds__(512, 4) void k_conv_mfma(const unsigned short* __restrict__ hb,
                                                      const unsigned short* __restrict__ Wb,
                                                      const float* __restrict__ cba,
                                                      const float* __restrict__ cbb,
                                                      unsigned short* __restrict__ uout) {
    __shared__ __align__(16) char smem[65536];
    int f = blockIdx.y;
    int r0 = blockIdx.x * 2;
    int tid = threadIdx.x;
    const unsigned short* base = hb + (size_t)f * 524288;

    int wid = tid >> 6, lane = tid & 63;
    int lhi = lane >> 4, llo = lane & 15;
    int row_off = wid & 1;
    int mbase = ((wid >> 1) & 1) * 64;
    int nbase = (wid >> 2) * 2;          // col-half: nf fragments {0,1} or {2,3}

    auto ldA = [&](int it, short8* a) {
        const unsigned short* wp = Wb + ((size_t)(it * 128 + mbase + llo)) * 32 + lhi * 8;
#pragma unroll
        for (int mf = 0; mf < 4; ++mf) a[mf] = *(const short8*)(wp + mf * 16 * 32);
    };
    auto ldB = [&](int it, short8* b) {
        int t = it >> 2, cb = it & 3;
        int dy = t / 3 - 1, dx = t % 3 - 1;
        int prow = row_off + 1 + dy;
        int slot = cb * 4 + lhi;
#pragma unroll
        for (int nf = 0; nf < 2; ++nf) {
            int c = (nbase + nf) * 16 + llo;
            int cdx = c + dx;
            bool valid = ((unsigned)cdx < 64u);
            int cr = valid ? cdx : c;
            int byteoff = ((prow * 64 + cr) << 8) + ((slot ^ (cr & 15)) << 4);
            short8 bb = *(const short8*)(smem + byteoff);
            b[nf] = valid ? bb : (short8)0;
        }
    };

    short8 aC[4], aN[4], aN2[4], bC[2], bN[2];
    ldA(0, aC);
    ldA(1, aN);

    for (int j = tid; j < 4096; j += 512) {
        int row = j >> 10;
        int cig = (j >> 6) & 15;
        int col = j & 63;
        int gr = r0 - 1 + row;
        short8 v = (short8)0;
        if ((unsigned)gr < 64u) {
            const unsigned short* p = base + (size_t)(cig * 8) * 4096 + gr * 64 + col;
#pragma unroll
            for (int e = 0; e < 8; ++e) v[e] = (short)p[(size_t)e * 4096];
        }
        int byteoff = ((row * 64 + col) << 8) + ((cig ^ (col & 15)) << 4);
        *(short8*)(smem + byteoff) = v;
    }
    __syncthreads();

    f32x4 acc[4][2];
#pragma unroll
    for (int mf = 0; mf < 4; ++mf)
#pragma unroll
        for (int nf = 0; nf < 2; ++nf) acc[mf][nf] = (f32x4)0.f;

    ldB(0, bC);
#pragma unroll
    for (int it = 0; it < 36; ++it) {
        if (it < 34) ldA(it + 2, aN2);
        if (it < 35) ldB(it + 1, bN);
        __builtin_amdgcn_s_setprio(1);
#pragma unroll
        for (int mf = 0; mf < 4; ++mf)
#pragma unroll
            for (int nf = 0; nf < 2; ++nf)
                acc[mf][nf] = __builtin_amdgcn_mfma_f32_16x16x32_bf16(aC[mf], bC[nf], acc[mf][nf], 0, 0, 0);
        __builtin_amdgcn_s_setprio(0);
#pragma unroll
        for (int k = 0; k < 4; ++k) { aC[k] = aN[k]; aN[k] = aN2[k]; }
#pragma unroll
        for (int k = 0; k < 2; ++k) bC[k] = bN[k];
    }

    int grow = r0 + row_off;
#pragma unroll
    for (int mf = 0; mf < 4; ++mf) {
#pragma unroll
        for (int r = 0; r < 4; ++r) {
            int co = mbase + mf * 16 + lhi * 4 + r;
            float bias = (co < 64) ? cba[co] : cbb[co - 64];
            unsigned short* op = uout + ((size_t)f * 128 + co) * 4096 + (size_t)grow * 64;
#pragma unroll
            for (int nf = 0; nf < 2; ++nf)
                op[(nbase + nf) * 16 + llo] = f2bf(acc[mf][nf][r] + bias);
        }
    }
}

// ---------------------------------------------------------------- k_helm (512 threads)
__global__ __launch_bounds__(512) void k_helm(const unsigned short* __restrict__ uin,
                                              unsigned short* __restrict__ uo,
                                              float* __restrict__ partials) {
    int bid = blockIdx.x;
    int f = bid >> 6, c = bid & 63;
    int tid = threadIdx.x;
    __shared__ float2 G[64 * ST], twl[64];
    __shared__ float red[32];
    if (tid < 64) {
        float sn, cs;
        sincosf(-(2.0f * PI_F / 64.0f) * (float)tid, &sn, &cs);
        twl[tid] = make_float2(cs, sn);
    }
    const unsigned short* u0 = uin + ((size_t)f * 128 + c) * 4096;
    const unsigned short* u1 = u0 + (size_t)64 * 4096;
    for (int i4 = tid; i4 < 1024; i4 += 512) {
        u16x4 a = ((const u16x4*)u0)[i4];
        u16x4 b = ((const u16x4*)u1)[i4];
        int r = i4 >> 4, w = (i4 & 15) << 2;
#pragma unroll
        for (int e = 0; e < 4; ++e)
            G[sw(r, w + e)] = make_float2(bf2f(a[e]), bf2f(b[e]));
    }
    __syncthreads();
    fftRowsA<-1>(G, twl, tid); __syncthreads();
    fftRowsB<-1>(G, tid);      __syncthreads();
    fftColsA<-1>(G, twl, tid); __syncthreads();
    fftColsB<-1>(G, tid);      __syncthreads();

    for (int i = tid; i < 1984; i += 512) {
        int mx = 1 + i % 31, my = i / 31;
        float2 Zk = G[sw(my, mx)];
        float2 Zm = G[sw((64 - my) & 63, 64 - mx)];
        float2 Vx = make_float2((Zk.x + Zm.x) * 0.5f, (Zk.y - Zm.y) * 0.5f);
        float2 Vy = make_float2((Zk.y + Zm.y) * 0.5f, (Zm.x - Zk.x) * 0.5f);
        float fx = (float)mx * (1.0f / 64.0f);
        float fy = (float)(my < 32 ? my : my - 64) * (1.0f / 64.0f);
        float inv = 1.0f / (fx * fx + fy * fy);
        float Pr = (fx * Vx.x + fy * Vy.x) * inv;
        float Pi = (fx * Vx.y + fy * Vy.y) * inv;
        Vx.x -= fx * Pr; Vx.y -= fx * Pi;
        Vy.x -= fy * Pr; Vy.y -= fy * Pi;
        G[sw(my, mx)] = make_float2(Vx.x - Vy.y, Vx.y + Vy.x);
        G[sw((64 - my) & 63, 64 - mx)] = make_float2(Vx.x + Vy.y, Vy.x - Vx.y);
    }
    if (tid < 64) {
        int mx = (tid >= 32) ? 32 : 0;
        int r = tid & 31;
        float fx = (float)mx * (1.0f / 64.0f);
        if (r == 0) {
#pragma unroll
            for (int q = 0; q < 2; ++q) {
                int my = q * 32;
                float fy = (my == 0) ? 0.f : -0.5f;
                float k2 = fx * fx + fy * fy;
                float2 Z = G[sw(my, mx)];
                float vx = Z.x, vy = Z.y;
                if (k2 > 0.f) {
                    float P = (fx * vx + fy * vy) / k2;
                    vx -= fx * P; vy -= fy * P;
                }
                G[sw(my, mx)] = make_float2(vx, vy);
            }
        } else {
            int my = r, my2 = 64 - r;
            float fy = (float)my * (1.0f / 64.0f);
            float inv = 1.0f / (fx * fx + fy * fy);
            float2 Zk = G[sw(my, mx)];
            float2 Zm = G[sw(my2, mx)];
            float2 Vx = make_float2((Zk.x + Zm.x) * 0.5f, (Zk.y - Zm.y) * 0.5f);
            float2 Vy = make_float2((Zk.y + Zm.y) * 0.5f, (Zm.x - Zk.x) * 0.5f);
            float Pr = (fx * Vx.x + fy * Vy.x) * inv;
            float Pi = (fx * Vx.y + fy * Vy.y) * inv;
            float2 Xk = make_float2(Vx.x - fx * Pr, Vx.y - fx * Pi);
            float2 Yk = make_float2(Vy.x - fy * Pr, Vy.y - fy * Pi);
            float P2r = (fx * Vx.x - fy * Vy.x) * inv;
            float P2i = (-fx * Vx.y + fy * Vy.y) * inv;
            float2 Xk2 = make_float2(Vx.x - fx * P2r, -Vx.y - fx * P2i);
            float2 Yk2 = make_float2(Vy.x + fy * P2r, -Vy.y + fy * P2i);
            float2 Xh = make_float2((Xk.x + Xk2.x) * 0.5f, (Xk.y - Xk2.y) * 0.5f);
            float2 Yh = make_float2((Yk.x + Yk2.x) * 0.5f, (Yk.y - Yk2.y) * 0.5f);
            G[sw(my, mx)]  = make_float2(Xh.x - Yh.y, Xh.y + Yh.x);
            G[sw(my2, mx)] = make_float2(Xh.x + Yh.y, Yh.x - Xh.y);
        }
    }
    __syncthreads();
    fftColsA<1>(G, twl, tid); __syncthreads();
    fftColsB<1>(G, tid);      __syncthreads();
    fftRowsA<1>(G, twl, tid); __syncthreads();
    fftRowsB<1>(G, tid);      __syncthreads();

    unsigned short* o0 = uo + ((size_t)f * 128 + c) * 4096;
    unsigned short* o1 = o0 + (size_t)64 * 4096;
    float s0 = 0.f, q0 = 0.f, s1 = 0.f, q1 = 0.f;
    for (int i4 = tid; i4 < 1024; i4 += 512) {
        int r = i4 >> 4, w = (i4 & 15) << 2;
        u16x4 oa, ob;
#pragma unroll
        for (int e = 0; e < 4; ++e) {
            float2 v = G[sw(r, w + e)];
            float a = v.x * (1.0f / 4096.0f);
            float b = v.y * (1.0f / 4096.0f);
            s0 += a; q0 += a * a; s1 += b; q1 += b * b;
            oa[e] = f2bf(a); ob[e] = f2bf(b);
        }
        ((u16x4*)o0)[i4] = oa;
        ((u16x4*)o1)[i4] = ob;
    }
    for (int off = 32; off > 0; off >>= 1) {
        s0 += __shfl_xor(s0, off, 64); q0 += __shfl_xor(q0, off, 64);
        s1 += __shfl_xor(s1, off, 64); q1 += __shfl_xor(q1, off, 64);
    }
    if ((tid & 63) == 0) {
        int w6 = tid >> 6;
        red[w6 * 4 + 0] = s0; red[w6 * 4 + 1] = q0;
        red[w6 * 4 + 2] = s1; red[w6 * 4 + 3] = q1;
    }
    __syncthreads();
    if (tid == 0) {
        float S0 = 0.f, Q0 = 0.f, S1 = 0.f, Q1 = 0.f;
#pragma unroll
        for (int w6 = 0; w6 < 8; ++w6) {
            S0 += red[w6 * 4 + 0]; Q0 += red[w6 * 4 + 1];
            S1 += red[w6 * 4 + 2]; Q1 += red[w6 * 4 + 3];
        }
        float* pp = partials + ((size_t)f * 64 + c) * 4;
        pp[0] = S0; pp[1] = Q0; pp[2] = S1; pp[3] = Q1;
    }
}

// ---------------------------------------------------------------- k_gnapply (fused gnfin)
__global__ __launch_bounds__(256) void k_gnapply(const unsigned short* __restrict__ u,
                                                 const float* __restrict__ partials,
                                                 const float* __restrict__ gnw,
                                                 const float* __restrict__ gnb,
                                                 float* __restrict__ out) {
    int bid = blockIdx.x;
    int fg = bid >> 6;            // f*4 + g
    int f = fg >> 2, g = fg & 3;
    int lane = threadIdx.x & 63;
    const float4* p4 = (const float4*)partials;
    float s = 0.f, q = 0.f;
    if (lane < 32) {
        float4 p = p4[f * 64 + (g & 1) * 32 + lane];
        if (g < 2) { s = p.x; q = p.y; } else { s = p.z; q = p.w; }
    }
#pragma unroll
    for (int off = 16; off > 0; off >>= 1) {
        s += __shfl_xor(s, off, 64);
        q += __shfl_xor(q, off, 64);
    }
    s = __shfl(s, 0, 64);
    q = __shfl(q, 0, 64);
    float mu = s * (1.0f / 131072.0f);
    float rsig = rsqrtf(q * (1.0f / 131072.0f) - mu * mu + 1e-5f);

    size_t i8 = (size_t)bid * 256 + threadIdx.x;
    u16x8 v = ((const u16x8*)u)[i8];
    int c = (bid >> 1) & 127;
    float sc = rsig * gnw[c];
    float sh = gnb[c] - mu * sc;
    float4 r0, r1;
    r0.x = bf2f(v[0]) * sc + sh; r0.y = bf2f(v[1]) * sc + sh;
    r0.z = bf2f(v[2]) * sc + sh; r0.w = bf2f(v[3]) * sc + sh;
    r1.x = bf2f(v[4]) * sc + sh; r1.y = bf2f(v[5]) * sc + sh;
    r1.z = bf2f(v[6]) * sc + sh; r1.w = bf2f(v[7]) * sc + sh;
    ((float4*)out)[i8 * 2]     = r0;
    ((float4*)out)[i8 * 2 + 1] = r1;
}

// ---------------------------------------------------------------- launch
extern "C" void kernel_launch(void* const* d_in, const int* in_sizes, int n_in,
                              void* d_out, int out_size, void* d_ws, size_t ws_size,
                              hipStream_t stream) {
    (void)in_sizes; (void)n_in; (void)out_size; (void)ws_size;
    const float* x   = (const float*)d_in[0];
    const float* dts = (const float*)d_in[1];
    const float* gw  = (const float*)d_in[2];
    const float* gb  = (const float*)d_in[3];
    const float* cwa = (const float*)d_in[4];
    const float* cwb = (const float*)d_in[5];
    const float* cba = (const float*)d_in[6];
    const float* cbb = (const float*)d_in[7];
    const float* gnw = (const float*)d_in[8];
    const float* gnb = (const float*)d_in[9];
    float* out = (float*)d_out;
    char* ws = (char*)d_ws;

    unsigned*       Sb  = (unsigned*)ws;                       // 34,603,008 B
    unsigned short* Hb  = (unsigned short*)(ws + 34603008);    // 33,554,432 B
    unsigned short* Ub  = (unsigned short*)(ws + 68157440);    // 33,554,432 B
    unsigned short* H1b = (unsigned short*)(ws + 101711872);   // 33,554,432 B
    float*  stats    = (float*)(ws + 135266304);
    float2* A        = (float2*)(ws + 135282688);
    float2* Xt       = (float2*)(ws + 135315456);
    float*  partials = (float*)(ws + 135349248);
    unsigned short* Wb = (unsigned short*)ws;                  // aliases Sb (dead after irfft2b)

    k_rfft2s<<<2048, 512, 0, stream>>>(x, Sb, stats);
    k_params<<<16, 256, 0, stream>>>(stats, gw, gb, dts, A, Xt);
    k_scan<<<528, 256, 0, stream>>>(Sb, A, Xt);
    k_irfft2b<<<2048, 512, 0, stream>>>(Sb, Hb);
    k_wprep<<<576, 256, 0, stream>>>(cwa, cwb, Wb);
    k_conv_mfma<<<dim3(32, 32), 512, 0, stream>>>(Hb, Wb, cba, cbb, Ub);
    k_helm<<<2048, 512, 0, stream>>>(Ub, H1b, partials);
    k_gnapply<<<8192, 256, 0, stream>>>(H1b, partials, gnw, gnb, out);
}

// Round 21
// 191.156 us; speedup vs baseline: 1.1346x; 1.1346x over previous
//
#include <hip/hip_runtime.h>
#include <math.h>

#define PI_F 3.14159265358979323846f
#define ST 66   // float2 row stride of the 64x64 complex grid

typedef __attribute__((ext_vector_type(8))) short short8;
typedef __attribute__((ext_vector_type(4))) float f32x4;
typedef __attribute__((ext_vector_type(4))) unsigned short u16x4;
typedef __attribute__((ext_vector_type(8))) unsigned short u16x8;
typedef __attribute__((ext_vector_type(4))) unsigned uint4v;

static __device__ __forceinline__ int sw(int row, int intra) {
    return row * ST + (intra ^ (row & 7));
}

static __device__ __forceinline__ unsigned short f2bf(float x) {
    unsigned u = __float_as_uint(x);
    unsigned r = (u + 0x7FFF + ((u >> 16) & 1)) >> 16;
    return (unsigned short)r;
}
static __device__ __forceinline__ float bf2f(unsigned short u) {
    return __uint_as_float(((unsigned)u) << 16);
}
static __device__ __forceinline__ float2 unpk(unsigned v) {
    return make_float2(bf2f((unsigned short)(v & 0xffff)), bf2f((unsigned short)(v >> 16)));
}

static __device__ __forceinline__ float2 cadd(float2 a, float2 b) { return make_float2(a.x + b.x, a.y + b.y); }
static __device__ __forceinline__ float2 csub(float2 a, float2 b) { return make_float2(a.x - b.x, a.y - b.y); }
static __device__ __forceinline__ float2 cmul(float2 a, float2 b) { return make_float2(a.x * b.x - a.y * b.y, a.x * b.y + a.y * b.x); }
static __device__ __forceinline__ float2 cmulc(float2 a, float2 b) { return make_float2(a.x * b.x + a.y * b.y, a.y * b.x - a.x * b.y); }

template <int S>
static __device__ __forceinline__ void dft8(float2* z) {
    const float RT = 0.70710678118654752440f;
    float2 ee0 = cadd(z[0], z[4]), ee1 = csub(z[0], z[4]);
    float2 eo0 = cadd(z[2], z[6]), eo1 = csub(z[2], z[6]);
    float2 oe0 = cadd(z[1], z[5]), oe1 = csub(z[1], z[5]);
    float2 oo0 = cadd(z[3], z[7]), oo1 = csub(z[3], z[7]);
    float2 ieo1 = make_float2(-S * eo1.y, S * eo1.x);
    float2 ioo1 = make_float2(-S * oo1.y, S * oo1.x);
    float2 E0 = cadd(ee0, eo0), E2 = csub(ee0, eo0);
    float2 E1 = cadd(ee1, ieo1), E3 = csub(ee1, ieo1);
    float2 O0 = cadd(oe0, oo0), O2 = csub(oe0, oo0);
    float2 O1 = cadd(oe1, ioo1), O3 = csub(oe1, ioo1);
    float2 w1O1 = make_float2(RT * (O1.x - S * O1.y), RT * (S * O1.x + O1.y));
    float2 w3O3 = make_float2(RT * (-O3.x - S * O3.y), RT * (S * O3.x - O3.y));
    float2 iO2  = make_float2(-S * O2.y, S * O2.x);
    z[0] = cadd(E0, O0);   z[4] = csub(E0, O0);
    z[1] = cadd(E1, w1O1); z[5] = csub(E1, w1O1);
    z[2] = cadd(E2, iO2);  z[6] = csub(E2, iO2);
    z[3] = cadd(E3, w3O3); z[7] = csub(E3, w3O3);
}

// ---- 512-thread FFT phases: 1 slot per thread (s = tid in [0,512)) ----
template <int S>
static __device__ __forceinline__ void fftRowsA(float2* G, const float2* twl, int s) {
    int row = s >> 3, b = s & 7;
    float2 z[8];
#pragma unroll
    for (int a = 0; a < 8; ++a) z[a] = G[sw(row, 8 * a + b)];
    dft8<S>(z);
#pragma unroll
    for (int c = 0; c < 8; ++c) {
        float2 t = twl[(b * c) & 63];
        G[sw(row, 8 * c + b)] = (S < 0) ? cmul(z[c], t) : cmulc(z[c], t);
    }
}
template <int S>
static __device__ __forceinline__ void fftRowsB(float2* G, int s) {
    int r0 = s >> 3, c = s & 7;
    float2 z0[8];
#pragma unroll
    for (int b = 0; b < 8; ++b) z0[b] = G[sw(r0, 8 * c + b)];
    dft8<S>(z0);
    __syncthreads();
#pragma unroll
    for (int d = 0; d < 8; ++d) G[sw(r0, c + 8 * d)] = z0[d];
}
template <int S>
static __device__ __forceinline__ void fftColsA(float2* G, const float2* twl, int s) {
    int col = s & 63, b = s >> 6;
    float2 z[8];
#pragma unroll
    for (int a = 0; a < 8; ++a) z[a] = G[sw(8 * a + b, col)];
    dft8<S>(z);
#pragma unroll
    for (int c = 0; c < 8; ++c) {
        float2 t = twl[(b * c) & 63];
        G[sw(8 * c + b, col)] = (S < 0) ? cmul(z[c], t) : cmulc(z[c], t);
    }
}
template <int S>
static __device__ __forceinline__ void fftColsB(float2* G, int s) {
    int col = s & 63, c0 = s >> 6;
    float2 z0[8];
#pragma unroll
    for (int b = 0; b < 8; ++b) z0[b] = G[sw(8 * c0 + b, col)];
    dft8<S>(z0);
    __syncthreads();
#pragma unroll
    for (int d = 0; d < 8; ++d) G[sw(c0 + 8 * d, col)] = z0[d];
}

// ---------------------------------------------------------------- k_params
__global__ __launch_bounds__(256) void k_params(const float* __restrict__ stats,
                                                const float* __restrict__ gw,
                                                const float* __restrict__ gb,
                                                const float* __restrict__ dts,
                                                float2* __restrict__ A,
                                                float2* __restrict__ Xt) {
    int idx = blockIdx.x * 256 + threadIdx.x;
    int c = idx & 127;
    int bt = idx >> 7;
    const float* st = stats + bt * 128;
    float nu = gb[c], om = gb[c + 128];
    for (int k = 0; k < 128; ++k) {
        float s = st[k];
        nu += s * gw[k * 256 + c];
        om += s * gw[k * 256 + c + 128];
    }
    float dt = dts[bt];
    float lre = -fabsf(nu);
    float lim = om;
    float mag = sqrtf(lre * lre + lim * lim);
    float er = expf(lre * dt);
    float sn, cs;
    sincosf(lim * dt, &sn, &cs);
    float2 Av = make_float2(er * cs, er * sn);
    float2 X;
    if (mag < 1e-6f) {
        X = make_float2(dt, 0.f);
    } else {
        float ar = Av.x - 1.f, ai = Av.y;
        float inv = 1.f / (mag * mag);
        X = make_float2((ar * lre + ai * lim) * inv, (ai * lre - ar * lim) * inv);
    }
    A[idx] = Av;
    Xt[idx] = X;
}

// ---------------------------------------------------------------- k_rfft2s (512 threads)
__global__ __launch_bounds__(512) void k_rfft2s(const float* __restrict__ xin,
                                                unsigned* __restrict__ Sb,
                                                float* __restrict__ stats) {
    int p = blockIdx.x, tid = threadIdx.x;
    __shared__ float2 G[64 * ST], twl[64];
    __shared__ float red[16];
    if (tid < 64) {
        float sn, cs;
        sincosf(-(2.0f * PI_F / 64.0f) * (float)tid, &sn, &cs);
        twl[tid] = make_float2(cs, sn);
    }
    const float* x0 = xin + (size_t)(2 * p) * 4096;
    const float* x1 = x0 + 4096;
    float s0 = 0.f, s1 = 0.f;
    for (int i4 = tid; i4 < 1024; i4 += 512) {
        float4 a = ((const float4*)x0)[i4];
        float4 b = ((const float4*)x1)[i4];
        s0 += a.x + a.y + a.z + a.w;
        s1 += b.x + b.y + b.z + b.w;
        int r = i4 >> 4, w = (i4 & 15) << 2;
        G[sw(r, w + 0)] = make_float2(a.x, b.x);
        G[sw(r, w + 1)] = make_float2(a.y, b.y);
        G[sw(r, w + 2)] = make_float2(a.z, b.z);
        G[sw(r, w + 3)] = make_float2(a.w, b.w);
    }
    for (int off = 32; off > 0; off >>= 1) {
        s0 += __shfl_xor(s0, off, 64);
        s1 += __shfl_xor(s1, off, 64);
    }
    if ((tid & 63) == 0) { red[(tid >> 6) * 2] = s0; red[(tid >> 6) * 2 + 1] = s1; }
    __syncthreads();
    if (tid < 2) {
        float t = 0.f;
#pragma unroll
        for (int w6 = 0; w6 < 8; ++w6) t += red[tid + 2 * w6];
        stats[2 * p + tid] = t * (1.0f / 4096.0f);
    }
    fftRowsA<-1>(G, twl, tid); __syncthreads();
    fftRowsB<-1>(G, tid);      __syncthreads();
    fftColsA<-1>(G, twl, tid); __syncthreads();
    fftColsB<-1>(G, tid);      __syncthreads();

    unsigned* o0 = Sb + (size_t)(2 * p) * 2112;
    unsigned* o1 = o0 + 2112;
    for (int i = tid; i < 2112; i += 512) {
        int my = i / 33, mx = i - my * 33;
        float2 Zk = G[sw(my, mx)];
        float2 Zm = G[sw((64 - my) & 63, (64 - mx) & 63)];
        float a0 = (Zk.x + Zm.x) * (0.5f / 64.0f);
        float a1 = (Zk.y - Zm.y) * (0.5f / 64.0f);
        float b0 = (Zk.y + Zm.y) * (0.5f / 64.0f);
        float b1 = (Zm.x - Zk.x) * (0.5f / 64.0f);
        o0[i] = (unsigned)f2bf(a0) | ((unsigned)f2bf(a1) << 16);
        o1[i] = (unsigned)f2bf(b0) | ((unsigned)f2bf(b1) << 16);
    }
}

// ---------------------------------------------------------------- k_scan (x4 vectorized, 16B/lane)
__global__ __launch_bounds__(256) void k_scan(unsigned* __restrict__ Sb,
                                              const float2* __restrict__ A,
                                              const float2* __restrict__ Xt) {
    int tid = blockIdx.x * 256 + threadIdx.x;   // 135168 total = 528 blocks
    int s = tid % 528;
    int c = (tid / 528) & 127;
    int b = tid / (528 * 128);
    float2 h0 = make_float2(0.f, 0.f), h1 = h0, h2 = h0, h3 = h0;
    for (int t = 0; t < 16; ++t) {
        int bt = b * 16 + t;
        float2 a = A[bt * 128 + c];
        float2 xt = Xt[bt * 128 + c];
        size_t off = ((size_t)(bt * 128 + c)) * 2112 + 4 * s;
        uint4v v = *(uint4v*)(Sb + off);
        float2 x0 = cmul(unpk(v[0]), xt);
        float2 x1 = cmul(unpk(v[1]), xt);
        float2 x2 = cmul(unpk(v[2]), xt);
        float2 x3 = cmul(unpk(v[3]), xt);
        h0 = make_float2(a.x * h0.x - a.y * h0.y + x0.x, a.x * h0.y + a.y * h0.x + x0.y);
        h1 = make_float2(a.x * h1.x - a.y * h1.y + x1.x, a.x * h1.y + a.y * h1.x + x1.y);
        h2 = make_float2(a.x * h2.x - a.y * h2.y + x2.x, a.x * h2.y + a.y * h2.x + x2.y);
        h3 = make_float2(a.x * h3.x - a.y * h3.y + x3.x, a.x * h3.y + a.y * h3.x + x3.y);
        uint4v o;
        o[0] = (unsigned)f2bf(h0.x) | ((unsigned)f2bf(h0.y) << 16);
        o[1] = (unsigned)f2bf(h1.x) | ((unsigned)f2bf(h1.y) << 16);
        o[2] = (unsigned)f2bf(h2.x) | ((unsigned)f2bf(h2.y) << 16);
        o[3] = (unsigned)f2bf(h3.x) | ((unsigned)f2bf(h3.y) << 16);
        *(uint4v*)(Sb + off) = o;
    }
}

// ---------------------------------------------------------------- k_irfft2b (512 threads)
__global__ __launch_bounds__(512) void k_irfft2b(const unsigned* __restrict__ Sb,
                                                 unsigned short* __restrict__ hb) {
    int p = blockIdx.x, tid = threadIdx.x;
    __shared__ float2 G[64 * ST], twl[64];
    if (tid < 64) {
        float sn, cs;
        sincosf(-(2.0f * PI_F / 64.0f) * (float)tid, &sn, &cs);
        twl[tid] = make_float2(cs, sn);
    }
    const unsigned* i0 = Sb + (size_t)(2 * p) * 2112;
    const unsigned* i1 = i0 + 2112;
    for (int i = tid; i < 1984; i += 512) {
        int mx = 1 + i % 31, my = i / 31;
        int idx = my * 33 + mx;
        float2 a = unpk(i0[idx]);
        float2 b = unpk(i1[idx]);
        G[sw(my, mx)] = make_float2(a.x - b.y, a.y + b.x);
        G[sw((64 - my) & 63, 64 - mx)] = make_float2(a.x + b.y, b.x - a.y);
    }
    if (tid < 64) {
        int mx = (tid >= 32) ? 32 : 0;
        int r = tid & 31;
        if (r == 0) {
#pragma unroll
            for (int q = 0; q < 2; ++q) {
                int my = q * 32;
                float2 a = unpk(i0[my * 33 + mx]);
                float2 b = unpk(i1[my * 33 + mx]);
                G[sw(my, mx)] = make_float2(a.x, b.x);     // imag dropped
            }
        } else {
            int my = r, my2 = 64 - r;
            float2 A0 = unpk(i0[my * 33 + mx]),  B0 = unpk(i0[my2 * 33 + mx]);
            float2 A1 = unpk(i1[my * 33 + mx]),  B1 = unpk(i1[my2 * 33 + mx]);
            float2 V0 = make_float2((A0.x + B0.x) * 0.5f, (A0.y - B0.y) * 0.5f);
            float2 V1 = make_float2((A1.x + B1.x) * 0.5f, (A1.y - B1.y) * 0.5f);
            G[sw(my, mx)]  = make_float2(V0.x - V1.y, V0.y + V1.x);
            G[sw(my2, mx)] = make_float2(V0.x + V1.y, V1.x - V0.y);
        }
    }
    __syncthreads();
    fftColsA<1>(G, twl, tid); __syncthreads();
    fftColsB<1>(G, tid);      __syncthreads();
    fftRowsA<1>(G, twl, tid); __syncthreads();
    fftRowsB<1>(G, tid);      __syncthreads();

    unsigned short* h0 = hb + (size_t)(2 * p) * 4096;
    unsigned short* h1 = h0 + 4096;
    for (int i4 = tid; i4 < 1024; i4 += 512) {
        int r = i4 >> 4, w = (i4 & 15) << 2;
        u16x4 oa, ob;
#pragma unroll
        for (int e = 0; e < 4; ++e) {
            float2 v = G[sw(r, w + e)];
            oa[e] = f2bf(v.x * (1.0f / 64.0f));
            ob[e] = f2bf(v.y * (1.0f / 64.0f));
        }
        ((u16x4*)h0)[i4] = oa;
        ((u16x4*)h1)[i4] = ob;
    }
}

// ---------------------------------------------------------------- k_wprep
__global__ __launch_bounds__(256) void k_wprep(const float* __restrict__ cwa,
                                               const float* __restrict__ cwb,
                                               unsigned short* __restrict__ Wb) {
    int idx = blockIdx.x * 256 + threadIdx.x;
    int kl = idx & 31;
    int m = (idx >> 5) & 127;
    int tcb = idx >> 12;
    int cb = tcb & 3, t = tcb >> 2;
    int ci = cb * 32 + kl;
    int mm = m & 63, cc = ci & 63;
    float w;
    if (m < 64) w = (ci < 64) ? cwa[(mm * 64 + cc) * 9 + t] : -cwb[(mm * 64 + cc) * 9 + t];
    else        w = (ci < 64) ? cwb[(mm * 64 + cc) * 9 + t] :  cwa[(mm * 64 + cc) * 9 + t];
    if (m == ci && t == 4) w += 1.0f;
    Wb[idx] = f2bf(w);
}

// ---------------------------------------------------------------- k_conv_mfma (best: 256 thr, 2-deep A)
__global__ __launch_bounds__(256, 2) void k_conv_mfma(const unsigned short* __restrict__ hb,
                                                      const unsigned short* __restrict__ Wb,
                                                      const float* __restrict__ cba,
                                                      const float* __restrict__ cbb,
                                                      unsigned short* __restrict__ uout) {
    __shared__ __align__(16) char smem[65536];
    int f = blockIdx.y;
    int r0 = blockIdx.x * 2;
    int tid = threadIdx.x;
    const unsigned short* base = hb + (size_t)f * 524288;

    int wid = tid >> 6, lane = tid & 63;
    int lhi = lane >> 4, llo = lane & 15;
    int row_off = wid & 1;
    int mbase = (wid >> 1) * 64;

    auto ldA = [&](int it, short8* a) {
        const unsigned short* wp = Wb + ((size_t)(it * 128 + mbase + llo)) * 32 + lhi * 8;
#pragma unroll
        for (int mf = 0; mf < 4; ++mf) a[mf] = *(const short8*)(wp + mf * 16 * 32);
    };
    auto ldB = [&](int it, short8* b) {
        int t = it >> 2, cb = it & 3;
        int dy = t / 3 - 1, dx = t % 3 - 1;
        int prow = row_off + 1 + dy;
        int slot = cb * 4 + lhi;
#pragma unroll
        for (int nf = 0; nf < 4; ++nf) {
            int c = nf * 16 + llo;
            int cdx = c + dx;
            bool valid = ((unsigned)cdx < 64u);
            int cr = valid ? cdx : c;
            int byteoff = ((prow * 64 + cr) << 8) + ((slot ^ (cr & 15)) << 4);
            short8 bb = *(const short8*)(smem + byteoff);
            b[nf] = valid ? bb : (short8)0;
        }
    };

    short8 aC[4], aN[4], aN2[4], bC[4], bN[4];
    ldA(0, aC);
    ldA(1, aN);

    for (int j = tid; j < 4096; j += 256) {
        int row = j >> 10;
        int cig = (j >> 6) & 15;
        int col = j & 63;
        int gr = r0 - 1 + row;
        short8 v = (short8)0;
        if ((unsigned)gr < 64u) {
            const unsigned short* p = base + (size_t)(cig * 8) * 4096 + gr * 64 + col;
#pragma unroll
            for (int e = 0; e < 8; ++e) v[e] = (short)p[(size_t)e * 4096];
        }
        int byteoff = ((row * 64 + col) << 8) + ((cig ^ (col & 15)) << 4);
        *(short8*)(smem + byteoff) = v;
    }
    __syncthreads();

    f32x4 acc[4][4];
#pragma unroll
    for (int mf = 0; mf < 4; ++mf)
#pragma unroll
        for (int nf = 0; nf < 4; ++nf) acc[mf][nf] = (f32x4)0.f;

    ldB(0, bC);
#pragma unroll
    for (int it = 0; it < 36; ++it) {
        if (it < 34) ldA(it + 2, aN2);
        if (it < 35) ldB(it + 1, bN);
        __builtin_amdgcn_s_setprio(1);
#pragma unroll
        for (int mf = 0; mf < 4; ++mf)
#pragma unroll
            for (int nf = 0; nf < 4; ++nf)
                acc[mf][nf] = __builtin_amdgcn_mfma_f32_16x16x32_bf16(aC[mf], bC[nf], acc[mf][nf], 0, 0, 0);
        __builtin_amdgcn_s_setprio(0);
#pragma unroll
        for (int k = 0; k < 4; ++k) { aC[k] = aN[k]; aN[k] = aN2[k]; bC[k] = bN[k]; }
    }

    int grow = r0 + row_off;
#pragma unroll
    for (int mf = 0; mf < 4; ++mf) {
#pragma unroll
        for (int r = 0; r < 4; ++r) {
            int co = mbase + mf * 16 + lhi * 4 + r;
            float bias = (co < 64) ? cba[co] : cbb[co - 64];
            unsigned short* op = uout + ((size_t)f * 128 + co) * 4096 + (size_t)grow * 64;
#pragma unroll
            for (int nf = 0; nf < 4; ++nf)
                op[nf * 16 + llo] = f2bf(acc[mf][nf][r] + bias);
        }
    }
}

// ---------------------------------------------------------------- k_helm (512 threads)
__global__ __launch_bounds__(512) void k_helm(const unsigned short* __restrict__ uin,
                                              unsigned short* __restrict__ uo,
                                              float* __restrict__ partials) {
    int bid = blockIdx.x;
    int f = bid >> 6, c = bid & 63;
    int tid = threadIdx.x;
    __shared__ float2 G[64 * ST], twl[64];
    __shared__ float red[32];
    if (tid < 64) {
        float sn, cs;
        sincosf(-(2.0f * PI_F / 64.0f) * (float)tid, &sn, &cs);
        twl[tid] = make_float2(cs, sn);
    }
    const unsigned short* u0 = uin + ((size_t)f * 128 + c) * 4096;
    const unsigned short* u1 = u0 + (size_t)64 * 4096;
    for (int i4 = tid; i4 < 1024; i4 += 512) {
        u16x4 a = ((const u16x4*)u0)[i4];
        u16x4 b = ((const u16x4*)u1)[i4];
        int r = i4 >> 4, w = (i4 & 15) << 2;
#pragma unroll
        for (int e = 0; e < 4; ++e)
            G[sw(r, w + e)] = make_float2(bf2f(a[e]), bf2f(b[e]));
    }
    __syncthreads();
    fftRowsA<-1>(G, twl, tid); __syncthreads();
    fftRowsB<-1>(G, tid);      __syncthreads();
    fftColsA<-1>(G, twl, tid); __syncthreads();
    fftColsB<-1>(G, tid);      __syncthreads();

    for (int i = tid; i < 1984; i += 512) {
        int mx = 1 + i % 31, my = i / 31;
        float2 Zk = G[sw(my, mx)];
        float2 Zm = G[sw((64 - my) & 63, 64 - mx)];
        float2 Vx = make_float2((Zk.x + Zm.x) * 0.5f, (Zk.y - Zm.y) * 0.5f);
        float2 Vy = make_float2((Zk.y + Zm.y) * 0.5f, (Zm.x - Zk.x) * 0.5f);
        float fx = (float)mx * (1.0f / 64.0f);
        float fy = (float)(my < 32 ? my : my - 64) * (1.0f / 64.0f);
        float inv = 1.0f / (fx * fx + fy * fy);
        float Pr = (fx * Vx.x + fy * Vy.x) * inv;
        float Pi = (fx * Vx.y + fy * Vy.y) * inv;
        Vx.x -= fx * Pr; Vx.y -= fx * Pi;
        Vy.x -= fy * Pr; Vy.y -= fy * Pi;
        G[sw(my, mx)] = make_float2(Vx.x - Vy.y, Vx.y + Vy.x);
        G[sw((64 - my) & 63, 64 - mx)] = make_float2(Vx.x + Vy.y, Vy.x - Vx.y);
    }
    if (tid < 64) {
        int mx = (tid >= 32) ? 32 : 0;
        int r = tid & 31;
        float fx = (float)mx * (1.0f / 64.0f);
        if (r == 0) {
#pragma unroll
            for (int q = 0; q < 2; ++q) {
                int my = q * 32;
                float fy = (my == 0) ? 0.f : -0.5f;
                float k2 = fx * fx + fy * fy;
                float2 Z = G[sw(my, mx)];
                float vx = Z.x, vy = Z.y;
                if (k2 > 0.f) {
                    float P = (fx * vx + fy * vy) / k2;
                    vx -= fx * P; vy -= fy * P;
                }
                G[sw(my, mx)] = make_float2(vx, vy);
            }
        } else {
            int my = r, my2 = 64 - r;
            float fy = (float)my * (1.0f / 64.0f);
            float inv = 1.0f / (fx * fx + fy * fy);
            float2 Zk = G[sw(my, mx)];
            float2 Zm = G[sw(my2, mx)];
            float2 Vx = make_float2((Zk.x + Zm.x) * 0.5f, (Zk.y - Zm.y) * 0.5f);
            float2 Vy = make_float2((Zk.y + Zm.y) * 0.5f, (Zm.x - Zk.x) * 0.5f);
            float Pr = (fx * Vx.x + fy * Vy.x) * inv;
            float Pi = (fx * Vx.y + fy * Vy.y) * inv;
            float2 Xk = make_float2(Vx.x - fx * Pr, Vx.y - fx * Pi);
            float2 Yk = make_float2(Vy.x - fy * Pr, Vy.y - fy * Pi);
            float P2r = (fx * Vx.x - fy * Vy.x) * inv;
            float P2i = (-fx * Vx.y + fy * Vy.y) * inv;
            float2 Xk2 = make_float2(Vx.x - fx * P2r, -Vx.y - fx * P2i);
            float2 Yk2 = make_float2(Vy.x + fy * P2r, -Vy.y + fy * P2i);
            float2 Xh = make_float2((Xk.x + Xk2.x) * 0.5f, (Xk.y - Xk2.y) * 0.5f);
            float2 Yh = make_float2((Yk.x + Yk2.x) * 0.5f, (Yk.y - Yk2.y) * 0.5f);
            G[sw(my, mx)]  = make_float2(Xh.x - Yh.y, Xh.y + Yh.x);
            G[sw(my2, mx)] = make_float2(Xh.x + Yh.y, Yh.x - Xh.y);
        }
    }
    __syncthreads();
    fftColsA<1>(G, twl, tid); __syncthreads();
    fftColsB<1>(G, tid);      __syncthreads();
    fftRowsA<1>(G, twl, tid); __syncthreads();
    fftRowsB<1>(G, tid);      __syncthreads();

    unsigned short* o0 = uo + ((size_t)f * 128 + c) * 4096;
    unsigned short* o1 = o0 + (size_t)64 * 4096;
    float s0 = 0.f, q0 = 0.f, s1 = 0.f, q1 = 0.f;
    for (int i4 = tid; i4 < 1024; i4 += 512) {
        int r = i4 >> 4, w = (i4 & 15) << 2;
        u16x4 oa, ob;
#pragma unroll
        for (int e = 0; e < 4; ++e) {
            float2 v = G[sw(r, w + e)];
            float a = v.x * (1.0f / 4096.0f);
            float b = v.y * (1.0f / 4096.0f);
            s0 += a; q0 += a * a; s1 += b; q1 += b * b;
            oa[e] = f2bf(a); ob[e] = f2bf(b);
        }
        ((u16x4*)o0)[i4] = oa;
        ((u16x4*)o1)[i4] = ob;
    }
    for (int off = 32; off > 0; off >>= 1) {
        s0 += __shfl_xor(s0, off, 64); q0 += __shfl_xor(q0, off, 64);
        s1 += __shfl_xor(s1, off, 64); q1 += __shfl_xor(q1, off, 64);
    }
    if ((tid & 63) == 0) {
        int w6 = tid >> 6;
        red[w6 * 4 + 0] = s0; red[w6 * 4 + 1] = q0;
        red[w6 * 4 + 2] = s1; red[w6 * 4 + 3] = q1;
    }
    __syncthreads();
    if (tid == 0) {
        float S0 = 0.f, Q0 = 0.f, S1 = 0.f, Q1 = 0.f;
#pragma unroll
        for (int w6 = 0; w6 < 8; ++w6) {
            S0 += red[w6 * 4 + 0]; Q0 += red[w6 * 4 + 1];
            S1 += red[w6 * 4 + 2]; Q1 += red[w6 * 4 + 3];
        }
        float* pp = partials + ((size_t)f * 64 + c) * 4;
        pp[0] = S0; pp[1] = Q0; pp[2] = S1; pp[3] = Q1;
    }
}

// ---------------------------------------------------------------- k_gnapply (fused gnfin)
__global__ __launch_bounds__(256) void k_gnapply(const unsigned short* __restrict__ u,
                                                 const float* __restrict__ partials,
                                                 const float* __restrict__ gnw,
                                                 const float* __restrict__ gnb,
                                                 float* __restrict__ out) {
    int bid = blockIdx.x;
    int fg = bid >> 6;            // f*4 + g
    int f = fg >> 2, g = fg & 3;
    int lane = threadIdx.x & 63;
    const float4* p4 = (const float4*)partials;
    float s = 0.f, q = 0.f;
    if (lane < 32) {
        float4 p = p4[f * 64 + (g & 1) * 32 + lane];
        if (g < 2) { s = p.x; q = p.y; } else { s = p.z; q = p.w; }
    }
#pragma unroll
    for (int off = 16; off > 0; off >>= 1) {
        s += __shfl_xor(s, off, 64);
        q += __shfl_xor(q, off, 64);
    }
    s = __shfl(s, 0, 64);
    q = __shfl(q, 0, 64);
    float mu = s * (1.0f / 131072.0f);
    float rsig = rsqrtf(q * (1.0f / 131072.0f) - mu * mu + 1e-5f);

    size_t i8 = (size_t)bid * 256 + threadIdx.x;
    u16x8 v = ((const u16x8*)u)[i8];
    int c = (bid >> 1) & 127;
    float sc = rsig * gnw[c];
    float sh = gnb[c] - mu * sc;
    float4 r0, r1;
    r0.x = bf2f(v[0]) * sc + sh; r0.y = bf2f(v[1]) * sc + sh;
    r0.z = bf2f(v[2]) * sc + sh; r0.w = bf2f(v[3]) * sc + sh;
    r1.x = bf2f(v[4]) * sc + sh; r1.y = bf2f(v[5]) * sc + sh;
    r1.z = bf2f(v[6]) * sc + sh; r1.w = bf2f(v[7]) * sc + sh;
    ((float4*)out)[i8 * 2]     = r0;
    ((float4*)out)[i8 * 2 + 1] = r1;
}

// ---------------------------------------------------------------- launch
extern "C" void kernel_launch(void* const* d_in, const int* in_sizes, int n_in,
                              void* d_out, int out_size, void* d_ws, size_t ws_size,
                              hipStream_t stream) {
    (void)in_sizes; (void)n_in; (void)out_size; (void)ws_size;
    const float* x   = (const float*)d_in[0];
    const float* dts = (const float*)d_in[1];
    const float* gw  = (const float*)d_in[2];
    const float* gb  = (const float*)d_in[3];
    const float* cwa = (const float*)d_in[4];
    const float* cwb = (const float*)d_in[5];
    const float* cba = (const float*)d_in[6];
    const float* cbb = (const float*)d_in[7];
    const float* gnw = (const float*)d_in[8];
    const float* gnb = (const float*)d_in[9];
    float* out = (float*)d_out;
    char* ws = (char*)d_ws;

    unsigned*       Sb  = (unsigned*)ws;                       // 34,603,008 B
    unsigned short* Hb  = (unsigned short*)(ws + 34603008);    // 33,554,432 B
    unsigned short* Ub  = (unsigned short*)(ws + 68157440);    // 33,554,432 B
    unsigned short* H1b = (unsigned short*)(ws + 101711872);   // 33,554,432 B
    float*  stats    = (float*)(ws + 135266304);
    float2* A        = (float2*)(ws + 135282688);
    float2* Xt       = (float2*)(ws + 135315456);
    float*  partials = (float*)(ws + 135349248);
    unsigned short* Wb = (unsigned short*)ws;                  // aliases Sb (dead after irfft2b)

    k_rfft2s<<<2048, 512, 0, stream>>>(x, Sb, stats);
    k_params<<<16, 256, 0, stream>>>(stats, gw, gb, dts, A, Xt);
    k_scan<<<528, 256, 0, stream>>>(Sb, A, Xt);
    k_irfft2b<<<2048, 512, 0, stream>>>(Sb, Hb);
    k_wprep<<<576, 256, 0, stream>>>(cwa, cwb, Wb);
    k_conv_mfma<<<dim3(32, 32), 256, 0, stream>>>(Hb, Wb, cba, cbb, Ub);
    k_helm<<<2048, 512, 0, stream>>>(Ub, H1b, partials);
    k_gnapply<<<8192, 256, 0, stream>>>(H1b, partials, gnw, gnb, out);
}